// Round 6
// baseline (24923.112 us; speedup 1.0000x reference)
//
#include <hip/hip_runtime.h>
#include <hip/hip_bf16.h>

// Swin block: B=8, H=W=128, C=192, NH=6, HD=32, WS=8, SHIFT=4, N=64, NW=256
// ROUND 6: inputs/outputs are FLOAT32 (per reference dtypes). Zero-workspace,
// all-VALU, fully fused per-window. LDS staging in bf16 (fits 160 KiB budget).

typedef __hip_bfloat16 bf16;

__device__ __forceinline__ float b2f(bf16 v) { return __bfloat162float(v); }
__device__ __forceinline__ bf16 f2b(float f) { return __float2bfloat16(f); }

__device__ __forceinline__ int lab3(int v) {   // region label along one axis
    return v < 120 ? 0 : (v < 124 ? 1 : 2);    // slices (0,-8),(-8,-4),(-4,None)
}

// ---- K1: per-window fused LN1 + shift + QKV + attention + proj + residual --
__global__ __launch_bounds__(256) void k_win(const float* __restrict__ x,
                                             const float* __restrict__ g,
                                             const float* __restrict__ bt,
                                             const float* __restrict__ qw,
                                             const float* __restrict__ qbias,
                                             const float* __restrict__ rpb,
                                             const float* __restrict__ pw,
                                             const float* __restrict__ pbias,
                                             float* __restrict__ o1) {
    __shared__ __align__(16) bf16 A[64 * 192];       // LN1 output tile (24.6 KB)
    __shared__ __align__(16) bf16 QKV[3 * 6 * 2048]; // [which][head][tok][32] (73.7 KB)
    __shared__ __align__(16) bf16 AO[64 * 192];      // attention out tile (24.6 KB)
    int wid = blockIdx.x;                 // b*256 + wh*16 + ww
    int b = wid >> 8, widx = wid & 255;
    int wh = widx >> 4, ww = widx & 15;
    int tid = threadIdx.x, wave = tid >> 6, lane = tid & 63;

    // --- Phase 1: LN1 + cyclic shift into A ---
    {
        float g0 = g[lane], g1 = g[lane + 64], g2 = g[lane + 128];
        float c0 = bt[lane], c1 = bt[lane + 64], c2 = bt[lane + 128];
        for (int t = wave; t < 64; t += 4) {
            int i = t >> 3, j = t & 7;
            int sh = (wh * 8 + i + 4) & 127;   // roll(-4)
            int sw = (ww * 8 + j + 4) & 127;
            size_t tok = (size_t)b * 16384 + sh * 128 + sw;
            const float* px = x + tok * 192;
            float v0 = px[lane], v1 = px[lane + 64], v2 = px[lane + 128];
            float s = v0 + v1 + v2, ss = v0 * v0 + v1 * v1 + v2 * v2;
#pragma unroll
            for (int o = 32; o > 0; o >>= 1) { s += __shfl_xor(s, o); ss += __shfl_xor(ss, o); }
            float mu = s * (1.f / 192.f);
            float var = fmaxf(ss * (1.f / 192.f) - mu * mu, 0.f);
            float rs = rsqrtf(var + 1e-5f);
            A[t * 192 + lane]       = f2b((v0 - mu) * rs * g0 + c0);
            A[t * 192 + lane + 64]  = f2b((v1 - mu) * rs * g1 + c1);
            A[t * 192 + lane + 128] = f2b((v2 - mu) * rs * g2 + c2);
        }
    }
    __syncthreads();

    // --- Phase 2: QKV dot products -> QKV LDS ---
    for (int e = tid; e < 64 * 576; e += 256) {
        int tok = e / 576, col = e % 576;
        float acc = qbias[col];
        const float* wr = qw + (size_t)col * 192;
        const bf16* ar = A + tok * 192;
        for (int k = 0; k < 192; ++k) acc += b2f(ar[k]) * wr[k];
        int which = col / 192, cc = col % 192;
        int head = cc >> 5, d = cc & 31;
        QKV[which * 12288 + head * 2048 + tok * 32 + d] = f2b(acc);
    }
    __syncthreads();

    // --- Phase 3: attention (6 heads x 64 queries = 384 work items) ---
    const float SC = 0.1767766952966369f;  // 1/sqrt(32)
    for (int u = tid; u < 384; u += 256) {
        int h = u >> 6, qi = u & 63;
        const bf16* Q = QKV + h * 2048;
        const bf16* K = QKV + 12288 + h * 2048;
        const bf16* V = QKV + 24576 + h * 2048;
        int yi = qi >> 3, xi = qi & 7;
        int li = lab3(wh * 8 + yi) * 3 + lab3(ww * 8 + xi);
        float S[64];
        float mx = -1e30f;
        for (int kj = 0; kj < 64; ++kj) {
            float s = 0.f;
            for (int d = 0; d < 32; ++d) s += b2f(Q[qi * 32 + d]) * b2f(K[kj * 32 + d]);
            int yj = kj >> 3, xj = kj & 7;
            int lj = lab3(wh * 8 + yj) * 3 + lab3(ww * 8 + xj);
            int rel = (yi - yj + 7) * 15 + (xi - xj + 7);
            float v = s * SC + rpb[rel * 6 + h];
            if (li != lj) v -= 100.f;
            S[kj] = v;
            mx = fmaxf(mx, v);
        }
        float sum = 0.f;
        for (int kj = 0; kj < 64; ++kj) { S[kj] = __expf(S[kj] - mx); sum += S[kj]; }
        float inv = 1.f / sum;
        for (int d = 0; d < 32; ++d) {
            float o = 0.f;
            for (int kj = 0; kj < 64; ++kj) o += S[kj] * b2f(V[kj * 32 + d]);
            AO[qi * 192 + h * 32 + d] = f2b(o * inv);
        }
    }
    __syncthreads();

    // --- Phase 4: proj + window reverse + un-shift + residual -> o1 (d_out) --
    for (int e = tid; e < 64 * 192; e += 256) {
        int tok = e / 192, col = e % 192;
        float acc = pbias[col];
        const float* wr = pw + (size_t)col * 192;
        const bf16* ar = AO + tok * 192;
        for (int k = 0; k < 192; ++k) acc += b2f(ar[k]) * wr[k];
        int i = tok >> 3, j = tok & 7;
        int dh = (wh * 8 + i + 4) & 127;   // roll(+4)
        int dw = (ww * 8 + j + 4) & 127;
        size_t dst = ((size_t)b * 16384 + dh * 128 + dw) * 192 + col;
        o1[dst] = acc + x[dst];
    }
}

// ---- K2: LN2 + MLP (fc1 + leaky + fc2 + residual), in-place on d_out -------
__global__ __launch_bounds__(256) void s_mlp(float* __restrict__ o1,
                                             const float* __restrict__ g2,
                                             const float* __restrict__ bt2,
                                             const float* __restrict__ w1,
                                             const float* __restrict__ b1,
                                             const float* __restrict__ w2,
                                             const float* __restrict__ b2) {
    __shared__ __align__(16) bf16 As[64 * 192];   // LN2 tile (24.6 KB)
    __shared__ __align__(16) bf16 Hs[64 * 768];   // leaky(fc1) tile (98.3 KB)
    int tid = threadIdx.x, wave = tid >> 6, lane = tid & 63;
    size_t tok0 = (size_t)blockIdx.x * 64;

    {   // LN2 (block-local)
        float g0 = g2[lane], g1 = g2[lane + 64], gg = g2[lane + 128];
        float c0 = bt2[lane], c1 = bt2[lane + 64], c2 = bt2[lane + 128];
        for (int t = wave; t < 64; t += 4) {
            const float* px = o1 + (tok0 + t) * 192;
            float v0 = px[lane], v1 = px[lane + 64], v2 = px[lane + 128];
            float s = v0 + v1 + v2, ss = v0 * v0 + v1 * v1 + v2 * v2;
#pragma unroll
            for (int o = 32; o > 0; o >>= 1) { s += __shfl_xor(s, o); ss += __shfl_xor(ss, o); }
            float mu = s * (1.f / 192.f);
            float var = fmaxf(ss * (1.f / 192.f) - mu * mu, 0.f);
            float rs = rsqrtf(var + 1e-5f);
            As[t * 192 + lane]       = f2b((v0 - mu) * rs * g0 + c0);
            As[t * 192 + lane + 64]  = f2b((v1 - mu) * rs * g1 + c1);
            As[t * 192 + lane + 128] = f2b((v2 - mu) * rs * gg + c2);
        }
    }
    __syncthreads();

    // fc1 + leaky -> Hs
    for (int e = tid; e < 64 * 768; e += 256) {
        int tok = e / 768, f = e % 768;
        float acc = b1[f];
        const float* wr = w1 + (size_t)f * 192;
        const bf16* ar = As + tok * 192;
        for (int k = 0; k < 192; ++k) acc += b2f(ar[k]) * wr[k];
        acc = acc > 0.f ? acc : 0.2f * acc;
        Hs[tok * 768 + f] = f2b(acc);
    }
    __syncthreads();

    // fc2 + residual (in-place; each element owned by one thread)
    for (int e = tid; e < 64 * 192; e += 256) {
        int tok = e / 192, c = e % 192;
        float acc = b2[c];
        const float* wr = w2 + (size_t)c * 768;
        const bf16* hr = Hs + tok * 768;
        for (int k = 0; k < 768; ++k) acc += b2f(hr[k]) * wr[k];
        size_t idx = (tok0 + tok) * 192 + c;
        o1[idx] = acc + o1[idx];
    }
}

// ---------------- launch ----------------------------------------------------
extern "C" void kernel_launch(void* const* d_in, const int* in_sizes, int n_in,
                              void* d_out, int out_size, void* d_ws, size_t ws_size,
                              hipStream_t stream) {
    const float* x     = (const float*)d_in[0];
    const float* n1g   = (const float*)d_in[1];
    const float* n1b   = (const float*)d_in[2];
    const float* qkvw  = (const float*)d_in[3];
    const float* qkvb  = (const float*)d_in[4];
    const float* projw = (const float*)d_in[5];
    const float* projb = (const float*)d_in[6];
    const float* rpb   = (const float*)d_in[7];
    const float* n2g   = (const float*)d_in[8];
    const float* n2b   = (const float*)d_in[9];
    const float* fc1w  = (const float*)d_in[10];
    const float* fc1b  = (const float*)d_in[11];
    const float* fc2w  = (const float*)d_in[12];
    const float* fc2b  = (const float*)d_in[13];

    float* o1 = (float*)d_out;   // residual stream lives entirely in d_out
    (void)d_ws; (void)ws_size;   // d_ws unused this round

    k_win<<<2048, 256, 0, stream>>>(x, n1g, n1b, qkvw, qkvb, rpb, projw, projb, o1);
    s_mlp<<<2048, 256, 0, stream>>>(o1, n2g, n2b, fc1w, fc1b, fc2w, fc2b);
}